// Round 4
// baseline (256.929 us; speedup 1.0000x reference)
//
#include <hip/hip_runtime.h>
#include <hip/hip_bf16.h>
#include <math.h>

// Problem constants (fixed by setup_inputs)
#define B 8
#define R 4096
#define C 1024
#define NROWS (B * R)          // 32768
#define F4_PER_ROW (C / 4)     // 256

// Native clang vector type — accepted by __builtin_nontemporal_store
// (HIP's float4 is a struct and is rejected).
typedef float vfloat4 __attribute__((ext_vector_type(4)));

// ---------------------------------------------------------------------------
// Kernel 1: row_magnitudes[row] = ||weight_params[row, :]||_2
// One wave per row, 4 waves/block -> 8192 blocks. float4 loads, double acc
// (ordering fidelity near the k-th order statistic; passes absmax=0.0).
// ---------------------------------------------------------------------------
__global__ void k_mags(const float* __restrict__ wp,
                       float* __restrict__ mags) {
    int row  = blockIdx.x * 4 + (threadIdx.x >> 6);
    int lane = threadIdx.x & 63;
    const vfloat4* p = (const vfloat4*)(wp + (size_t)row * C);
    double acc = 0.0;
#pragma unroll
    for (int j = 0; j < 4; ++j) {
        vfloat4 v = p[j * 64 + lane];
        acc += (double)v.x * v.x + (double)v.y * v.y +
               (double)v.z * v.z + (double)v.w * v.w;
    }
    for (int off = 32; off > 0; off >>= 1)
        acc += __shfl_down(acc, off, 64);
    if (lane == 0) mags[row] = (float)sqrt(acc);
}

// ---------------------------------------------------------------------------
// Kernel 2: per batch (8 blocks x 1024 threads): fused score + 4-pass radix
// select (exact k-th largest row norm via u32 bit-pattern monotonicity).
// Verified exact in R2 (absmax 0.0).
// ---------------------------------------------------------------------------
__global__ void k_select(const float* __restrict__ logits,
                         const float* __restrict__ sw,
                         const float* __restrict__ sb,
                         const float* __restrict__ mags,
                         float* __restrict__ thr) {
    __shared__ unsigned hist[256];
    __shared__ double dred[16];
    __shared__ unsigned sh_prefix;
    __shared__ int sh_krem;

    const int b = blockIdx.x, t = threadIdx.x;
    const int wave = t >> 6, lane = t & 63;

    // ---- Phase 0: rows_to_keep -------------------------------------------
    double a = (double)logits[b * C + t] * (double)sw[t];
    for (int off = 32; off > 0; off >>= 1)
        a += __shfl_down(a, off, 64);
    if (lane == 0) dred[wave] = a;
    __syncthreads();
    if (t == 0) {
        double s = (double)sb[0];
        for (int w = 0; w < 16; ++w) s += dred[w];
        double kf = 1.0 / (1.0 + exp(-s));
        int k = (int)(kf * (double)R);   // truncation, kf >= 0
        if (k < 1) k = 1;
        if (k > R) k = R;
        sh_krem = k;
        sh_prefix = 0u;
    }

    // ---- load this batch's norms into registers as sortable u32 ----------
    unsigned u[4];
#pragma unroll
    for (int j = 0; j < 4; ++j)
        u[j] = __float_as_uint(mags[b * R + t + j * 1024]);
    __syncthreads();   // sh_krem/sh_prefix visible

    // ---- Phase 1-4: radix select, high byte -> low byte -------------------
    const int shifts[4] = {24, 16, 8, 0};
    const unsigned maskH[4] = {0x00000000u, 0xFF000000u, 0xFFFF0000u, 0xFFFFFF00u};
#pragma unroll
    for (int p = 0; p < 4; ++p) {
        const int shift = shifts[p];
        const unsigned mh = maskH[p];
        if (t < 256) hist[t] = 0u;
        __syncthreads();
        const unsigned pref = sh_prefix;
        const int krem = sh_krem;
#pragma unroll
        for (int j = 0; j < 4; ++j) {
            if ((u[j] & mh) == pref)
                atomicAdd(&hist[(u[j] >> shift) & 255u], 1u);
        }
        __syncthreads();
        if (t < 64) {  // wave 0: suffix scan over 256 bins, 4 bins/lane
            unsigned h0 = hist[4 * t], h1 = hist[4 * t + 1],
                     h2 = hist[4 * t + 2], h3 = hist[4 * t + 3];
            unsigned s4 = h0 + h1 + h2 + h3;
            unsigned suf = s4;
            for (int off = 1; off < 64; off <<= 1) {
                unsigned tmp = __shfl_down(suf, off, 64);
                if (lane + off < 64) suf += tmp;
            }
            unsigned below = suf - s4;  // count in bins strictly above this group
            if ((int)suf >= krem && (int)below < krem) {
                unsigned hh[4] = {h0, h1, h2, h3};
                unsigned cum = below;
                for (int bb = 3; bb >= 0; --bb) {
                    cum += hh[bb];
                    if ((int)cum >= krem) {
                        sh_krem   = krem - (int)(cum - hh[bb]);
                        sh_prefix = pref | ((unsigned)(4 * t + bb) << shift);
                        break;
                    }
                }
            }
        }
        __syncthreads();
    }
    if (t == 0) thr[b] = __uint_as_float(sh_prefix);
}

// ---------------------------------------------------------------------------
// Kernel 3: out = wp * (mags[row] >= thr[batch]).
// 8 rows per block (4096 blocks x 256 threads), one float4/thread/row.
// VECTOR nontemporal store (single global_store_dwordx4 nt): coalesced, and
// keeps `out` from evicting wp's L3 lines during the read phase.
// (R2 bug: scalar NT stores -> 4B/lane @16B stride partial-line HBM writes.)
// ---------------------------------------------------------------------------
__global__ void k_apply(const float* __restrict__ wp,
                        const float* __restrict__ mags,
                        const float* __restrict__ thr,
                        float* __restrict__ out) {
    const int t = threadIdx.x;
    const int row0 = blockIdx.x * 8;           // 8 rows per block
    const int b = row0 >> 12;                  // all 8 rows in same batch
    const float tb = thr[b];
    const vfloat4* src = ((const vfloat4*)wp) + (size_t)row0 * F4_PER_ROW;
    vfloat4*       dst = ((vfloat4*)out)      + (size_t)row0 * F4_PER_ROW;
#pragma unroll
    for (int j = 0; j < 8; ++j) {
        float m = (mags[row0 + j] >= tb) ? 1.0f : 0.0f;
        vfloat4 v = src[j * F4_PER_ROW + t];
        v *= m;
        __builtin_nontemporal_store(v, &dst[j * F4_PER_ROW + t]);
    }
}

extern "C" void kernel_launch(void* const* d_in, const int* in_sizes, int n_in,
                              void* d_out, int out_size, void* d_ws, size_t ws_size,
                              hipStream_t stream) {
    const float* wp     = (const float*)d_in[0];  // [8,4096,1024]
    const float* logits = (const float*)d_in[1];  // [8,1024]
    const float* sw     = (const float*)d_in[2];  // [1024,1]
    const float* sb     = (const float*)d_in[3];  // [1]
    float* out = (float*)d_out;

    // Workspace: mags (32768 f32 = 128 KiB) | thr (8 f32)
    float* mags = (float*)d_ws;
    float* thr  = mags + NROWS;

    k_mags  <<<NROWS / 4, 256, 0, stream>>>(wp, mags);
    k_select<<<B, 1024, 0, stream>>>(logits, sw, sb, mags, thr);
    k_apply <<<NROWS / 8, 256, 0, stream>>>(wp, mags, thr, out);
}

// Round 5
// 245.283 us; speedup vs baseline: 1.0475x; 1.0475x over previous
//
#include <hip/hip_runtime.h>
#include <hip/hip_bf16.h>
#include <math.h>

// Problem constants (fixed by setup_inputs)
#define B 8
#define R 4096
#define C 1024
#define NROWS (B * R)          // 32768
#define F4_PER_ROW (C / 4)     // 256

// Native clang vector type — accepted by __builtin_nontemporal_store
// (HIP's float4 is a struct and is rejected).
typedef float vfloat4 __attribute__((ext_vector_type(4)));

// ---------------------------------------------------------------------------
// Kernel 1: row_magnitudes[row] = ||weight_params[row, :]||_2
// One wave per row, 4 waves/block -> 8192 blocks. float4 loads, double acc
// (ordering fidelity near the k-th order statistic; passes absmax=0.0).
// ---------------------------------------------------------------------------
__global__ void k_mags(const float* __restrict__ wp,
                       float* __restrict__ mags) {
    int row  = blockIdx.x * 4 + (threadIdx.x >> 6);
    int lane = threadIdx.x & 63;
    const vfloat4* p = (const vfloat4*)(wp + (size_t)row * C);
    double acc = 0.0;
#pragma unroll
    for (int j = 0; j < 4; ++j) {
        vfloat4 v = p[j * 64 + lane];
        acc += (double)v.x * v.x + (double)v.y * v.y +
               (double)v.z * v.z + (double)v.w * v.w;
    }
    for (int off = 32; off > 0; off >>= 1)
        acc += __shfl_down(acc, off, 64);
    if (lane == 0) mags[row] = (float)sqrt(acc);
}

// ---------------------------------------------------------------------------
// Kernel 2: per batch (8 blocks x 1024 threads): fused score + 4-pass radix
// select (exact k-th largest row norm via u32 bit-pattern monotonicity).
// Verified exact since R2 (absmax 0.0).
// ---------------------------------------------------------------------------
__global__ void k_select(const float* __restrict__ logits,
                         const float* __restrict__ sw,
                         const float* __restrict__ sb,
                         const float* __restrict__ mags,
                         float* __restrict__ thr) {
    __shared__ unsigned hist[256];
    __shared__ double dred[16];
    __shared__ unsigned sh_prefix;
    __shared__ int sh_krem;

    const int b = blockIdx.x, t = threadIdx.x;
    const int wave = t >> 6, lane = t & 63;

    // ---- Phase 0: rows_to_keep -------------------------------------------
    double a = (double)logits[b * C + t] * (double)sw[t];
    for (int off = 32; off > 0; off >>= 1)
        a += __shfl_down(a, off, 64);
    if (lane == 0) dred[wave] = a;
    __syncthreads();
    if (t == 0) {
        double s = (double)sb[0];
        for (int w = 0; w < 16; ++w) s += dred[w];
        double kf = 1.0 / (1.0 + exp(-s));
        int k = (int)(kf * (double)R);   // truncation, kf >= 0
        if (k < 1) k = 1;
        if (k > R) k = R;
        sh_krem = k;
        sh_prefix = 0u;
    }

    // ---- load this batch's norms into registers as sortable u32 ----------
    unsigned u[4];
#pragma unroll
    for (int j = 0; j < 4; ++j)
        u[j] = __float_as_uint(mags[b * R + t + j * 1024]);
    __syncthreads();   // sh_krem/sh_prefix visible

    // ---- Phase 1-4: radix select, high byte -> low byte -------------------
    const int shifts[4] = {24, 16, 8, 0};
    const unsigned maskH[4] = {0x00000000u, 0xFF000000u, 0xFFFF0000u, 0xFFFFFF00u};
#pragma unroll
    for (int p = 0; p < 4; ++p) {
        const int shift = shifts[p];
        const unsigned mh = maskH[p];
        if (t < 256) hist[t] = 0u;
        __syncthreads();
        const unsigned pref = sh_prefix;
        const int krem = sh_krem;
#pragma unroll
        for (int j = 0; j < 4; ++j) {
            if ((u[j] & mh) == pref)
                atomicAdd(&hist[(u[j] >> shift) & 255u], 1u);
        }
        __syncthreads();
        if (t < 64) {  // wave 0: suffix scan over 256 bins, 4 bins/lane
            unsigned h0 = hist[4 * t], h1 = hist[4 * t + 1],
                     h2 = hist[4 * t + 2], h3 = hist[4 * t + 3];
            unsigned s4 = h0 + h1 + h2 + h3;
            unsigned suf = s4;
            for (int off = 1; off < 64; off <<= 1) {
                unsigned tmp = __shfl_down(suf, off, 64);
                if (lane + off < 64) suf += tmp;
            }
            unsigned below = suf - s4;  // count in bins strictly above this group
            if ((int)suf >= krem && (int)below < krem) {
                unsigned hh[4] = {h0, h1, h2, h3};
                unsigned cum = below;
                for (int bb = 3; bb >= 0; --bb) {
                    cum += hh[bb];
                    if ((int)cum >= krem) {
                        sh_krem   = krem - (int)(cum - hh[bb]);
                        sh_prefix = pref | ((unsigned)(4 * t + bb) << shift);
                        break;
                    }
                }
            }
        }
        __syncthreads();
    }
    if (t == 0) thr[b] = __uint_as_float(sh_prefix);
}

// ---------------------------------------------------------------------------
// Kernel 3: out = wp * (mags[row] >= thr[batch]).
// 8 rows/block (4096 blocks x 256 threads), one float4/thread/row.
// NEW: masked rows (mask==0) write zeros WITHOUT reading wp — the only
// remaining real traffic cut (~50% of this kernel's reads on average).
// Branch is block-uniform (mask depends only on row), so no divergence.
// ---------------------------------------------------------------------------
__global__ void k_apply(const float* __restrict__ wp,
                        const float* __restrict__ mags,
                        const float* __restrict__ thr,
                        float* __restrict__ out) {
    const int t = threadIdx.x;
    const int row0 = blockIdx.x * 8;           // 8 rows per block
    const int b = row0 >> 12;                  // all 8 rows in same batch
    const float tb = thr[b];
    const vfloat4* src = ((const vfloat4*)wp) + (size_t)row0 * F4_PER_ROW;
    vfloat4*       dst = ((vfloat4*)out)      + (size_t)row0 * F4_PER_ROW;
#pragma unroll
    for (int j = 0; j < 8; ++j) {
        if (mags[row0 + j] >= tb) {
            vfloat4 v = src[j * F4_PER_ROW + t];
            __builtin_nontemporal_store(v, &dst[j * F4_PER_ROW + t]);
        } else {
            vfloat4 z = {0.0f, 0.0f, 0.0f, 0.0f};
            __builtin_nontemporal_store(z, &dst[j * F4_PER_ROW + t]);
        }
    }
}

extern "C" void kernel_launch(void* const* d_in, const int* in_sizes, int n_in,
                              void* d_out, int out_size, void* d_ws, size_t ws_size,
                              hipStream_t stream) {
    const float* wp     = (const float*)d_in[0];  // [8,4096,1024]
    const float* logits = (const float*)d_in[1];  // [8,1024]
    const float* sw     = (const float*)d_in[2];  // [1024,1]
    const float* sb     = (const float*)d_in[3];  // [1]
    float* out = (float*)d_out;

    // Workspace: mags (32768 f32 = 128 KiB) | thr (8 f32)
    float* mags = (float*)d_ws;
    float* thr  = mags + NROWS;

    k_mags  <<<NROWS / 4, 256, 0, stream>>>(wp, mags);
    k_select<<<B, 1024, 0, stream>>>(logits, sw, sb, mags, thr);
    k_apply <<<NROWS / 8, 256, 0, stream>>>(wp, mags, thr, out);
}